// Round 12
// baseline (1161.710 us; speedup 1.0000x reference)
//
#include <hip/hip_runtime.h>

#define NF 128
#define EPS 1e-5f
#define SLOPE 0.2f

typedef __attribute__((ext_vector_type(8))) short bf16x8;
typedef __attribute__((ext_vector_type(4))) float f32x4;

static __device__ __forceinline__ unsigned short f2bf(float f) {
  unsigned int u = __builtin_bit_cast(unsigned int, f);
  u += 0x7fffu + ((u >> 16) & 1u);
  return (unsigned short)(u >> 16);
}
static __device__ __forceinline__ float bflo(unsigned int u) {
  return __builtin_bit_cast(float, u << 16);
}
static __device__ __forceinline__ float bfhi(unsigned int u) {
  return __builtin_bit_cast(float, u & 0xffff0000u);
}
static __device__ __forceinline__ unsigned int pack2(float a, float b) {
  return (unsigned int)f2bf(a) | ((unsigned int)f2bf(b) << 16);
}

// ---------------- CSR build (round-5 structure: pos precompute, 1-pass fill) ----------------

__global__ void k_init_counts(int* counts, int n) {
  int i = blockIdx.x * 256 + threadIdx.x;
  if (i < n) counts[i] = 1;  // self-loop
}

__global__ void k_count(const int* __restrict__ dst, int* __restrict__ counts,
                        int* __restrict__ pos, int e) {
  int i = blockIdx.x * 256 + threadIdx.x;
  if (i < e) pos[i] = atomicAdd(&counts[dst[i]], 1);
}

__global__ void k_scan_part(const int* __restrict__ counts, int* __restrict__ partials, int n) {
  __shared__ int sd[256];
  int base = blockIdx.x * 2048;
  int sum = 0;
  for (int i = threadIdx.x; i < 2048; i += 256) {
    int idx = base + i;
    sum += (idx < n) ? counts[idx] : 0;
  }
  sd[threadIdx.x] = sum;
  __syncthreads();
  for (int s = 128; s > 0; s >>= 1) {
    if (threadIdx.x < s) sd[threadIdx.x] += sd[threadIdx.x + s];
    __syncthreads();
  }
  if (threadIdx.x == 0) partials[blockIdx.x] = sd[0];
}

__global__ void k_scan_mid(int* partials, int nb) {
  if (threadIdx.x == 0 && blockIdx.x == 0) {
    int acc = 0;
    for (int b = 0; b < nb; b++) { int v = partials[b]; partials[b] = acc; acc += v; }
  }
}

__global__ void k_scan_final(const int* __restrict__ counts, const int* __restrict__ partials,
                             int* __restrict__ offsets, int n) {
  __shared__ int sd[256];
  int t = threadIdx.x;
  int base = blockIdx.x * 2048;
  int local[8];
  int sum = 0;
#pragma unroll
  for (int j = 0; j < 8; j++) {
    int idx = base + t * 8 + j;
    int v = (idx < n) ? counts[idx] : 0;
    local[j] = sum;
    sum += v;
  }
  sd[t] = sum;
  __syncthreads();
  for (int st = 1; st < 256; st <<= 1) {
    int v = 0;
    if (t >= st) v = sd[t - st];
    __syncthreads();
    if (t >= st) sd[t] += v;
    __syncthreads();
  }
  int tb = partials[blockIdx.x] + (t > 0 ? sd[t - 1] : 0);
#pragma unroll
  for (int j = 0; j < 8; j++) {
    int idx = base + t * 8 + j;
    if (idx < n) offsets[idx] = tb + local[j];
  }
}

__global__ void k_selfloop(int* __restrict__ offsets, int* __restrict__ csr, int n, int total) {
  int i = blockIdx.x * 256 + threadIdx.x;
  if (i < n) csr[offsets[i]] = i;  // self-loop first (pos starts at 1)
  if (i == 0) offsets[n] = total;
}

__global__ void k_fill(const int* __restrict__ src, const int* __restrict__ dst,
                       const int* __restrict__ offsets, const int* __restrict__ pos,
                       int* __restrict__ csr, int e) {
  int i = blockIdx.x * 256 + threadIdx.x;
  if (i < e) csr[offsets[dst[i]] + pos[i]] = src[i];
}

// ---------------- converts ----------------

__global__ void k_f32_to_bf16(const float* __restrict__ x, unsigned short* __restrict__ o,
                              int n, int np) {
  int i = blockIdx.x * 256 + threadIdx.x;  // ushort4 units
  if (i >= np * (NF / 4)) return;
  int row = i >> 5;
  ushort4 ov;
  if (row < n) {
    float4 v = ((const float4*)x)[i];
    ov = make_ushort4(f2bf(v.x), f2bf(v.y), f2bf(v.z), f2bf(v.w));
  } else {
    ov = make_ushort4(0, 0, 0, 0);
  }
  ((ushort4*)o)[i] = ov;
}

__global__ void k_wt(const float* __restrict__ W0, const float* __restrict__ Wm,
                     const float* __restrict__ W5, const float* __restrict__ Wr,
                     const float* __restrict__ Wo, unsigned short* __restrict__ Wt) {
  int idx = blockIdx.x * 256 + threadIdx.x;  // 8 * 16384
  if (idx >= 8 * NF * NF) return;
  int mat = idx >> 14;
  int rem = idx & 16383;
  int r = rem >> 7;   // output col
  int k = rem & 127;  // k
  const float* W = (mat == 0) ? W0
                 : (mat <= 4) ? Wm + (size_t)(mat - 1) * NF * NF
                 : (mat == 5) ? W5
                 : (mat == 6) ? Wr : Wo;
  Wt[idx] = f2bf(W[k * NF + r]);
}

// ---------------- MFMA GEMM ----------------
// MODE 0: plain A; epilogue bf16 Cb (unguarded) + fused s/d row-dots.
// MODE 1: plain A; epilogue f32 Cf + bias, guarded.
// MODE 2: plain A; epilogue bf16 Cb + bias, unguarded.
// MODE 3: A = bf16(relu(bn(agg)) + res), written to hout IF hout != null;
//         epilogue like 0.
// MODE 4: A = bf16(bn(agg)); epilogue like 1.

template <int MODE>
__global__ __launch_bounds__(256) void k_gemm_mfma(
    const unsigned short* __restrict__ A, const unsigned short* __restrict__ Wt,
    const float* __restrict__ asrc, const float* __restrict__ adst,
    const float* __restrict__ bias, unsigned short* __restrict__ Cb,
    float* __restrict__ Cf, float* __restrict__ sv, float* __restrict__ dv, int n,
    const unsigned short* __restrict__ agg, const unsigned short* __restrict__ res,
    const float* __restrict__ scsh, unsigned short* __restrict__ hout) {
  int w = threadIdx.x >> 6;
  int l = threadIdx.x & 63;
  int lr = l & 15, lh = l >> 4;
  int row0 = blockIdx.x * 128 + w * 32;

  bf16x8 af[2][4];
  if (MODE <= 2) {
    const unsigned short* Ab = A + (size_t)(row0 + lr) * NF + lh * 8;
#pragma unroll
    for (int m = 0; m < 2; m++)
#pragma unroll
      for (int kk = 0; kk < 4; kk++)
        af[m][kk] = *(const bf16x8*)(Ab + m * 16 * NF + kk * 32);
  } else {
#pragma unroll
    for (int kk = 0; kk < 4; kk++) {
      int c0 = lh * 8 + kk * 32;
      float4 scA = *(const float4*)&scsh[c0];
      float4 scB = *(const float4*)&scsh[c0 + 4];
      float4 shA = *(const float4*)&scsh[128 + c0];
      float4 shB = *(const float4*)&scsh[128 + c0 + 4];
#pragma unroll
      for (int m = 0; m < 2; m++) {
        size_t base = (size_t)(row0 + lr + m * 16) * NF + c0;
        uint4 ag = *(const uint4*)(agg + base);
        float v0 = bflo(ag.x) * scA.x + shA.x;
        float v1 = bfhi(ag.x) * scA.y + shA.y;
        float v2 = bflo(ag.y) * scA.z + shA.z;
        float v3 = bfhi(ag.y) * scA.w + shA.w;
        float v4 = bflo(ag.z) * scB.x + shB.x;
        float v5 = bfhi(ag.z) * scB.y + shB.y;
        float v6 = bflo(ag.w) * scB.z + shB.z;
        float v7 = bfhi(ag.w) * scB.w + shB.w;
        if (MODE == 3) {
          uint4 rs = *(const uint4*)(res + base);
          v0 = fmaxf(v0, 0.f) + bflo(rs.x);
          v1 = fmaxf(v1, 0.f) + bfhi(rs.x);
          v2 = fmaxf(v2, 0.f) + bflo(rs.y);
          v3 = fmaxf(v3, 0.f) + bfhi(rs.y);
          v4 = fmaxf(v4, 0.f) + bflo(rs.z);
          v5 = fmaxf(v5, 0.f) + bfhi(rs.z);
          v6 = fmaxf(v6, 0.f) + bflo(rs.w);
          v7 = fmaxf(v7, 0.f) + bfhi(rs.w);
        }
        uint4 hv;
        hv.x = pack2(v0, v1);
        hv.y = pack2(v2, v3);
        hv.z = pack2(v4, v5);
        hv.w = pack2(v6, v7);
        if (MODE == 3 && hout) *(uint4*)(hout + base) = hv;
        af[m][kk] = __builtin_bit_cast(bf16x8, hv);
      }
    }
  }

  f32x4 acc[2][8];
#pragma unroll
  for (int m = 0; m < 2; m++)
#pragma unroll
    for (int nn = 0; nn < 8; nn++) acc[m][nn] = (f32x4){0.f, 0.f, 0.f, 0.f};

  const unsigned short* Bb = Wt + (size_t)lr * NF + lh * 8;
#pragma unroll
  for (int kk = 0; kk < 4; kk++) {
    bf16x8 bfr[8];
#pragma unroll
    for (int nn = 0; nn < 8; nn++)
      bfr[nn] = *(const bf16x8*)(Bb + nn * 16 * NF + kk * 32);
#pragma unroll
    for (int m = 0; m < 2; m++)
#pragma unroll
      for (int nn = 0; nn < 8; nn++)
        acc[m][nn] = __builtin_amdgcn_mfma_f32_16x16x32_bf16(af[m][kk], bfr[nn], acc[m][nn], 0, 0, 0);
  }

  if (MODE == 0 || MODE == 3) {
    float as[8], ad[8];
#pragma unroll
    for (int nn = 0; nn < 8; nn++) {
      as[nn] = asrc[nn * 16 + lr];
      ad[nn] = adst[nn * 16 + lr];
    }
#pragma unroll
    for (int m = 0; m < 2; m++) {
#pragma unroll
      for (int r = 0; r < 4; r++) {
        int row = row0 + m * 16 + lh * 4 + r;
        float sp = 0.f, dp = 0.f;
#pragma unroll
        for (int nn = 0; nn < 8; nn++) {
          float v = acc[m][nn][r];
          sp += v * as[nn];
          dp += v * ad[nn];
          Cb[(size_t)row * NF + nn * 16 + lr] = f2bf(v);
        }
#pragma unroll
        for (int mk = 8; mk > 0; mk >>= 1) {
          sp += __shfl_xor(sp, mk);
          dp += __shfl_xor(dp, mk);
        }
        if (lr == 0) { sv[row] = sp; dv[row] = dp; }
      }
    }
  } else if (MODE == 1 || MODE == 4) {
    float bcol[8];
#pragma unroll
    for (int nn = 0; nn < 8; nn++) bcol[nn] = bias[nn * 16 + lr];
#pragma unroll
    for (int m = 0; m < 2; m++)
#pragma unroll
      for (int r = 0; r < 4; r++) {
        int row = row0 + m * 16 + lh * 4 + r;
        if (row < n) {
#pragma unroll
          for (int nn = 0; nn < 8; nn++)
            Cf[(size_t)row * NF + nn * 16 + lr] = acc[m][nn][r] + bcol[nn];
        }
      }
  } else {
    float bcol[8];
#pragma unroll
    for (int nn = 0; nn < 8; nn++) bcol[nn] = bias[nn * 16 + lr];
#pragma unroll
    for (int m = 0; m < 2; m++)
#pragma unroll
      for (int r = 0; r < 4; r++) {
        int row = row0 + m * 16 + lh * 4 + r;
#pragma unroll
        for (int nn = 0; nn < 8; nn++)
          Cb[(size_t)row * NF + nn * 16 + lr] = f2bf(acc[m][nn][r] + bcol[nn]);
      }
  }
}

// ---------------- fused softmax + HALF-COLUMN gather + BN partial stats ----------------
// half = blockIdx & 1 -> with the %8 XCD round-robin, each XCD serves only one
// 64-column half of h (12.8 MB) -> per-XCD L2 traffic ~halved vs full rows.
// Softmax phase: IDENTICAL to round 7 (full wave, unconditional shfl only,
// LDS (src,w) table published per wave; wj==0 for lanes >= deg).
// Gather phase: 8 edge-slots (e8 = l>>3) x 8 col-lanes (c8 = l&7) x uint4 =
// same 16 B/lane and loads-per-instruction as round 7, 2-deep pipeline.
// Reduce over edge-slots AFTER reconvergence (xor 8/16/32).

__global__ __launch_bounds__(256) void k_attn_gather(
    const float* __restrict__ sv, const float* __restrict__ dv,
    const int* __restrict__ offs, const int* __restrict__ csr,
    const unsigned short* __restrict__ hbf, const float* __restrict__ bias,
    unsigned short* __restrict__ aggb, float* __restrict__ pstat, int n) {
  int w = threadIdx.x >> 6, l = threadIdx.x & 63;
  int half = blockIdx.x & 1;
  int chunk = blockIdx.x >> 1;
  int e8 = l >> 3, c8 = l & 7;
  int colbase = half * 64 + c8 * 8;
  int node0 = chunk * 16 + w * 4;
  float ps[8] = {0.f, 0.f, 0.f, 0.f, 0.f, 0.f, 0.f, 0.f};
  float qs[8] = {0.f, 0.f, 0.f, 0.f, 0.f, 0.f, 0.f, 0.f};
  float4 bv0 = *(const float4*)&bias[colbase];
  float4 bv1 = *(const float4*)&bias[colbase + 4];

  __shared__ uint2 s_pair[4][80];  // (src, w) table + 16 zero-pad slots
  if (l < 16) s_pair[w][64 + l] = make_uint2(0u, 0u);

  for (int ni = 0; ni < 4; ni++) {
    int node = node0 + ni;
    if (node >= n) break;
    int o0 = offs[node], o1 = offs[node + 1];
    int deg = o1 - o0;
    float di = dv[node];
    float a[8] = {0.f, 0.f, 0.f, 0.f, 0.f, 0.f, 0.f, 0.f};

    if (deg <= 64) {
      bool valid = l < deg;
      int srcj = valid ? csr[o0 + l] : 0;
      float ev = valid ? sv[srcj] + di : -1e30f;
      ev = ev >= 0.f ? ev : SLOPE * ev;
      float m = ev;
#pragma unroll
      for (int k2 = 32; k2 > 0; k2 >>= 1) m = fmaxf(m, __shfl_xor(m, k2));
      float pe = valid ? __expf(ev - m) : 0.f;
      float z = pe;
#pragma unroll
      for (int k2 = 32; k2 > 0; k2 >>= 1) z += __shfl_xor(z, k2);
      float wj = pe / z;  // == 0 for lanes l >= deg

      // all 64 lanes write -> slots [0,64) always fresh (wj==0 beyond deg)
      s_pair[w][l] = make_uint2((unsigned)srcj, __builtin_bit_cast(unsigned, wj));

      for (int j = e8; j < deg; j += 16) {
        uint2 pA = s_pair[w][j];
        uint2 pB = s_pair[w][j + 8];  // <= 71 < 80: live slot or zero pad
        float wA = __builtin_bit_cast(float, pA.y);
        float wB = __builtin_bit_cast(float, pB.y);
        uint4 hA = *(const uint4*)(hbf + (size_t)pA.x * NF + colbase);
        uint4 hB = *(const uint4*)(hbf + (size_t)pB.x * NF + colbase);
        a[0] += wA * bflo(hA.x) + wB * bflo(hB.x);
        a[1] += wA * bfhi(hA.x) + wB * bfhi(hB.x);
        a[2] += wA * bflo(hA.y) + wB * bflo(hB.y);
        a[3] += wA * bfhi(hA.y) + wB * bfhi(hB.y);
        a[4] += wA * bflo(hA.z) + wB * bflo(hB.z);
        a[5] += wA * bfhi(hA.z) + wB * bfhi(hB.z);
        a[6] += wA * bflo(hA.w) + wB * bflo(hB.w);
        a[7] += wA * bfhi(hA.w) + wB * bfhi(hB.w);
      }
    } else {
      float m = -1e30f;
      for (int j = o0 + l; j < o1; j += 64) {
        float ev = sv[csr[j]] + di;
        ev = ev >= 0.f ? ev : SLOPE * ev;
        m = fmaxf(m, ev);
      }
#pragma unroll
      for (int k2 = 32; k2 > 0; k2 >>= 1) m = fmaxf(m, __shfl_xor(m, k2));
      float z = 0.f;
      for (int j = o0 + l; j < o1; j += 64) {
        float ev = sv[csr[j]] + di;
        ev = ev >= 0.f ? ev : SLOPE * ev;
        z += __expf(ev - m);
      }
#pragma unroll
      for (int k2 = 32; k2 > 0; k2 >>= 1) z += __shfl_xor(z, k2);
      float inv = 1.f / z;
      for (int tt = o0 + e8; tt < o1; tt += 8) {  // divergent trips: no cross-lane ops
        int sI = csr[tt];
        float ev = sv[sI] + di;
        ev = ev >= 0.f ? ev : SLOPE * ev;
        float wI = __expf(ev - m) * inv;
        uint4 hv = *(const uint4*)(hbf + (size_t)sI * NF + colbase);
        a[0] += wI * bflo(hv.x);
        a[1] += wI * bfhi(hv.x);
        a[2] += wI * bflo(hv.y);
        a[3] += wI * bfhi(hv.y);
        a[4] += wI * bflo(hv.z);
        a[5] += wI * bfhi(hv.z);
        a[6] += wI * bflo(hv.w);
        a[7] += wI * bfhi(hv.w);
      }
    }
    // reconverged: reduce over the 8 edge slots (lane bits 3,4,5)
#pragma unroll
    for (int j = 0; j < 8; j++) {
      a[j] += __shfl_xor(a[j], 8);
      a[j] += __shfl_xor(a[j], 16);
      a[j] += __shfl_xor(a[j], 32);
    }
    if (e8 == 0) {
      a[0] += bv0.x; a[1] += bv0.y; a[2] += bv0.z; a[3] += bv0.w;
      a[4] += bv1.x; a[5] += bv1.y; a[6] += bv1.z; a[7] += bv1.w;
      uint4 ov;
      ov.x = pack2(a[0], a[1]);
      ov.y = pack2(a[2], a[3]);
      ov.z = pack2(a[4], a[5]);
      ov.w = pack2(a[6], a[7]);
      *(uint4*)(aggb + (size_t)node * NF + colbase) = ov;  // 8 lanes x 16B = 128B
#pragma unroll
      for (int j = 0; j < 8; j++) { ps[j] += a[j]; qs[j] += a[j] * a[j]; }
    }
  }

  __shared__ float red[4][8][17];
  if (e8 == 0) {
#pragma unroll
    for (int j = 0; j < 8; j++) {
      red[w][c8][j] = ps[j];
      red[w][c8][8 + j] = qs[j];
    }
  }
  __syncthreads();
  int t = threadIdx.x;
  if (t < 128) {
    int kind = t >> 6;   // 0 = sum, 1 = sumsq
    int cc = t & 63;     // col within this half
    int ci = cc >> 3, ck = (cc & 7) + 8 * kind;
    float v = red[0][ci][ck] + red[1][ci][ck] + red[2][ci][ck] + red[3][ci][ck];
    atomicAdd(&pstat[((blockIdx.x >> 1) & 63) * 256 + kind * 128 + half * 64 + cc], v);
  }
}

// ---------------- BN finalize ----------------

__global__ void k_bnfinal(float* __restrict__ pstat, const float* __restrict__ gamma,
                          const float* __restrict__ beta, float* __restrict__ scsh,
                          float ninv) {
  __shared__ float tot[256];
  int t = threadIdx.x;
  float v = 0.f;
  for (int s2 = 0; s2 < 64; s2++) {
    v += pstat[s2 * 256 + t];
    pstat[s2 * 256 + t] = 0.f;
  }
  tot[t] = v;
  __syncthreads();
  if (t < 128) {
    float mu = tot[t] * ninv;
    float var = tot[128 + t] * ninv - mu * mu;
    float sc = gamma[t] * rsqrtf(var + EPS);
    scsh[t] = sc;
    scsh[128 + t] = beta[t] - mu * sc;
  }
}

// ---------------- launcher ----------------

extern "C" void kernel_launch(void* const* d_in, const int* in_sizes, int n_in,
                              void* d_out, int out_size, void* d_ws, size_t ws_size,
                              hipStream_t stream) {
  (void)n_in; (void)out_size; (void)ws_size;
  const float* x     = (const float*)d_in[0];
  const int*   ei    = (const int*)d_in[1];
  const float* W0    = (const float*)d_in[2];
  const float* asrc0 = (const float*)d_in[3];
  const float* adst0 = (const float*)d_in[4];
  const float* b0    = (const float*)d_in[5];
  const float* Wm    = (const float*)d_in[6];
  const float* asrcm = (const float*)d_in[7];
  const float* adstm = (const float*)d_in[8];
  const float* bm    = (const float*)d_in[9];
  const float* W5    = (const float*)d_in[10];
  const float* asrc5 = (const float*)d_in[11];
  const float* adst5 = (const float*)d_in[12];
  const float* b5    = (const float*)d_in[13];
  const float* gammas= (const float*)d_in[14];
  const float* betas = (const float*)d_in[15];
  const float* Wr    = (const float*)d_in[16];
  const float* br    = (const float*)d_in[17];
  const float* Wo    = (const float*)d_in[18];
  const float* bo    = (const float*)d_in[19];

  const int n = in_sizes[0] / NF;
  const int np = (n + 127) & ~127;
  const int e = in_sizes[1] / 2;
  const int tot = e + n;
  const int* srcp = ei;
  const int* dstp = ei + e;

  char* w = (char*)d_ws;
  auto carve = [&](size_t bytes) {
    char* p = w;
    w += (bytes + 255) & ~(size_t)255;
    return p;
  };
  unsigned short* h_bf    = (unsigned short*)carve((size_t)np * NF * 2);
  unsigned short* hlin_bf = (unsigned short*)carve((size_t)np * NF * 2);
  unsigned short* res_bf  = (unsigned short*)carve((size_t)np * NF * 2);
  unsigned short* agg_bf  = (unsigned short*)carve((size_t)np * NF * 2);
  unsigned short* Wt      = (unsigned short*)carve((size_t)8 * NF * NF * 2);
  float* sv      = (float*)carve((size_t)np * 4);
  float* dv      = (float*)carve((size_t)np * 4);
  int*   csr     = (int*)carve((size_t)tot * 4);
  int*   offsets = (int*)carve((size_t)(n + 1) * 4);
  int*   counts  = (int*)carve((size_t)n * 4);
  int*   pos     = (int*)carve((size_t)e * 4);
  int*   partials= (int*)carve(64 * 4);
  float* pstat   = (float*)carve(64 * 256 * 4);
  float* scsh    = (float*)carve(256 * 4);

  int nb = (n + 2047) / 2048;

  // one-time converts
  k_wt<<<(8 * NF * NF + 255) / 256, 256, 0, stream>>>(W0, Wm, W5, Wr, Wo, Wt);
  k_f32_to_bf16<<<(np * (NF / 4) + 255) / 256, 256, 0, stream>>>(x, h_bf, n, np);

  // CSR build (round-5 structure)
  k_init_counts<<<(n + 255) / 256, 256, 0, stream>>>(counts, n);
  k_count<<<(e + 255) / 256, 256, 0, stream>>>(dstp, counts, pos, e);
  k_scan_part<<<nb, 256, 0, stream>>>(counts, partials, n);
  k_scan_mid<<<1, 64, 0, stream>>>(partials, nb);
  k_scan_final<<<nb, 256, 0, stream>>>(counts, partials, offsets, n);
  k_selfloop<<<(n + 255) / 256, 256, 0, stream>>>(offsets, csr, n, tot);
  k_fill<<<(e + 255) / 256, 256, 0, stream>>>(srcp, dstp, offsets, pos, csr, e);

  hipMemsetAsync(pstat, 0, 64 * 256 * 4, stream);

  int gemm_grid = np / 128;
  int gather_grid = 2 * ((n + 15) / 16);

  // residual = bf16(x @ Wr + br)
  k_gemm_mfma<2><<<gemm_grid, 256, 0, stream>>>(h_bf, Wt + 6 * NF * NF, nullptr, nullptr,
                                                br, res_bf, nullptr, nullptr, nullptr, n,
                                                nullptr, nullptr, nullptr, nullptr);

  for (int L = 0; L < 6; L++) {
    const float *als, *ald, *bl;
    if (L == 0)      { als = asrc0; ald = adst0; bl = b0; }
    else if (L <= 4) { als = asrcm + (L - 1) * NF; ald = adstm + (L - 1) * NF; bl = bm + (L - 1) * NF; }
    else             { als = asrc5; ald = adst5; bl = b5; }

    if (L == 0) {
      k_gemm_mfma<0><<<gemm_grid, 256, 0, stream>>>(h_bf, Wt, als, ald, nullptr, hlin_bf,
                                                    nullptr, sv, dv, n,
                                                    nullptr, nullptr, nullptr, nullptr);
    } else {
      const unsigned short* resb = (L == 1) ? res_bf : h_bf;
      // L == 5: h_5 is dead after this GEMM -> skip the hout store
      unsigned short* houtp = (L < 5) ? h_bf : nullptr;
      k_gemm_mfma<3><<<gemm_grid, 256, 0, stream>>>(nullptr, Wt + (size_t)L * NF * NF,
                                                    als, ald, nullptr, hlin_bf, nullptr, sv, dv, n,
                                                    agg_bf, resb, scsh, houtp);
    }

    k_attn_gather<<<gather_grid, 256, 0, stream>>>(sv, dv, offsets, csr, hlin_bf, bl,
                                                   agg_bf, pstat, n);
    k_bnfinal<<<1, 256, 0, stream>>>(pstat, gammas + L * NF, betas + L * NF, scsh, 1.0f / n);
  }

  // final: out = bn(agg_5) @ Wo + bo
  k_gemm_mfma<4><<<gemm_grid, 256, 0, stream>>>(nullptr, Wt + 7 * NF * NF, nullptr, nullptr,
                                                bo, nullptr, (float*)d_out, nullptr, nullptr, n,
                                                agg_bf, nullptr, scsh, nullptr);
}

// Round 13
// 884.185 us; speedup vs baseline: 1.3139x; 1.3139x over previous
//
#include <hip/hip_runtime.h>

#define NF 128
#define EPS 1e-5f
#define SLOPE 0.2f

typedef __attribute__((ext_vector_type(8))) short bf16x8;
typedef __attribute__((ext_vector_type(4))) float f32x4;

static __device__ __forceinline__ unsigned short f2bf(float f) {
  unsigned int u = __builtin_bit_cast(unsigned int, f);
  u += 0x7fffu + ((u >> 16) & 1u);
  return (unsigned short)(u >> 16);
}
static __device__ __forceinline__ float bf2f(unsigned short s) {
  return __builtin_bit_cast(float, (unsigned int)s << 16);
}
static __device__ __forceinline__ float bflo(unsigned int u) {
  return __builtin_bit_cast(float, u << 16);
}
static __device__ __forceinline__ float bfhi(unsigned int u) {
  return __builtin_bit_cast(float, u & 0xffff0000u);
}
static __device__ __forceinline__ unsigned int pack2(float a, float b) {
  return (unsigned int)f2bf(a) | ((unsigned int)f2bf(b) << 16);
}

// ---------------- CSR build ----------------

__global__ void k_init_counts(int* counts, int n) {
  int i = blockIdx.x * 256 + threadIdx.x;
  if (i < n) counts[i] = 1;  // self-loop
}

// count + per-edge position (atomic here; fill becomes atomic-free)
__global__ void k_count(const int* __restrict__ dst, int* __restrict__ counts,
                        int* __restrict__ pos, int e) {
  int i = blockIdx.x * 256 + threadIdx.x;
  if (i < e) pos[i] = atomicAdd(&counts[dst[i]], 1);
}

__global__ void k_scan_part(const int* __restrict__ counts, int* __restrict__ partials, int n) {
  __shared__ int sd[256];
  int base = blockIdx.x * 2048;
  int sum = 0;
  for (int i = threadIdx.x; i < 2048; i += 256) {
    int idx = base + i;
    sum += (idx < n) ? counts[idx] : 0;
  }
  sd[threadIdx.x] = sum;
  __syncthreads();
  for (int s = 128; s > 0; s >>= 1) {
    if (threadIdx.x < s) sd[threadIdx.x] += sd[threadIdx.x + s];
    __syncthreads();
  }
  if (threadIdx.x == 0) partials[blockIdx.x] = sd[0];
}

__global__ void k_scan_mid(int* partials, int nb) {
  if (threadIdx.x == 0 && blockIdx.x == 0) {
    int acc = 0;
    for (int b = 0; b < nb; b++) { int v = partials[b]; partials[b] = acc; acc += v; }
  }
}

__global__ void k_scan_final(const int* __restrict__ counts, const int* __restrict__ partials,
                             int* __restrict__ offsets, int n) {
  __shared__ int sd[256];
  int t = threadIdx.x;
  int base = blockIdx.x * 2048;
  int local[8];
  int sum = 0;
#pragma unroll
  for (int j = 0; j < 8; j++) {
    int idx = base + t * 8 + j;
    int v = (idx < n) ? counts[idx] : 0;
    local[j] = sum;
    sum += v;
  }
  sd[t] = sum;
  __syncthreads();
  for (int st = 1; st < 256; st <<= 1) {
    int v = 0;
    if (t >= st) v = sd[t - st];
    __syncthreads();
    if (t >= st) sd[t] += v;
    __syncthreads();
  }
  int tb = partials[blockIdx.x] + (t > 0 ? sd[t - 1] : 0);
#pragma unroll
  for (int j = 0; j < 8; j++) {
    int idx = base + t * 8 + j;
    if (idx < n) offsets[idx] = tb + local[j];
  }
}

__global__ void k_selfloop(int* __restrict__ offsets, int* __restrict__ csr, int n, int total) {
  int i = blockIdx.x * 256 + threadIdx.x;
  if (i < n) csr[offsets[i]] = i;  // self-loop first (pos starts at 1)
  if (i == 0) offsets[n] = total;
}

__global__ void k_fill(const int* __restrict__ src, const int* __restrict__ dst,
                       const int* __restrict__ offsets, const int* __restrict__ pos,
                       int* __restrict__ csr, int e) {
  int i = blockIdx.x * 256 + threadIdx.x;
  if (i < e) csr[offsets[dst[i]] + pos[i]] = src[i];
}

// ---------------- converts ----------------

__global__ void k_f32_to_bf16(const float* __restrict__ x, unsigned short* __restrict__ o,
                              int n, int np) {
  int i = blockIdx.x * 256 + threadIdx.x;  // ushort4 units
  if (i >= np * (NF / 4)) return;
  int row = i >> 5;
  ushort4 ov;
  if (row < n) {
    float4 v = ((const float4*)x)[i];
    ov = make_ushort4(f2bf(v.x), f2bf(v.y), f2bf(v.z), f2bf(v.w));
  } else {
    ov = make_ushort4(0, 0, 0, 0);
  }
  ((ushort4*)o)[i] = ov;
}

__global__ void k_wt(const float* __restrict__ W0, const float* __restrict__ Wm,
                     const float* __restrict__ W5, const float* __restrict__ Wr,
                     const float* __restrict__ Wo, unsigned short* __restrict__ Wt) {
  int idx = blockIdx.x * 256 + threadIdx.x;  // 8 * 16384
  if (idx >= 8 * NF * NF) return;
  int mat = idx >> 14;
  int rem = idx & 16383;
  int r = rem >> 7;   // output col
  int k = rem & 127;  // k
  const float* W = (mat == 0) ? W0
                 : (mat <= 4) ? Wm + (size_t)(mat - 1) * NF * NF
                 : (mat == 5) ? W5
                 : (mat == 6) ? Wr : Wo;
  Wt[idx] = f2bf(W[k * NF + r]);
}

// ---------------- MFMA GEMM ----------------
// MODE 0: C bf16 (unguarded, padded) + fused s/d row-dots.
// MODE 1: C f32 + bias, guarded (final output).
// MODE 2: C bf16 + bias, unguarded padded (residual init).

template <int MODE>
__global__ __launch_bounds__(256) void k_gemm_mfma(
    const unsigned short* __restrict__ A, const unsigned short* __restrict__ Wt,
    const float* __restrict__ asrc, const float* __restrict__ adst,
    const float* __restrict__ bias, unsigned short* __restrict__ Cb,
    float* __restrict__ Cf, float* __restrict__ sv, float* __restrict__ dv, int n) {
  int w = threadIdx.x >> 6;
  int l = threadIdx.x & 63;
  int lr = l & 15, lh = l >> 4;
  int row0 = blockIdx.x * 128 + w * 32;

  const unsigned short* Ab = A + (size_t)(row0 + lr) * NF + lh * 8;
  bf16x8 af[2][4];
#pragma unroll
  for (int m = 0; m < 2; m++)
#pragma unroll
    for (int kk = 0; kk < 4; kk++)
      af[m][kk] = *(const bf16x8*)(Ab + m * 16 * NF + kk * 32);

  f32x4 acc[2][8];
#pragma unroll
  for (int m = 0; m < 2; m++)
#pragma unroll
    for (int nn = 0; nn < 8; nn++) acc[m][nn] = (f32x4){0.f, 0.f, 0.f, 0.f};

  const unsigned short* Bb = Wt + (size_t)lr * NF + lh * 8;
#pragma unroll
  for (int kk = 0; kk < 4; kk++) {
    bf16x8 bfr[8];
#pragma unroll
    for (int nn = 0; nn < 8; nn++)
      bfr[nn] = *(const bf16x8*)(Bb + nn * 16 * NF + kk * 32);
#pragma unroll
    for (int m = 0; m < 2; m++)
#pragma unroll
      for (int nn = 0; nn < 8; nn++)
        acc[m][nn] = __builtin_amdgcn_mfma_f32_16x16x32_bf16(af[m][kk], bfr[nn], acc[m][nn], 0, 0, 0);
  }

  if (MODE == 0) {
    float as[8], ad[8];
#pragma unroll
    for (int nn = 0; nn < 8; nn++) {
      as[nn] = asrc[nn * 16 + lr];
      ad[nn] = adst[nn * 16 + lr];
    }
#pragma unroll
    for (int m = 0; m < 2; m++) {
#pragma unroll
      for (int r = 0; r < 4; r++) {
        int row = row0 + m * 16 + lh * 4 + r;
        float sp = 0.f, dp = 0.f;
#pragma unroll
        for (int nn = 0; nn < 8; nn++) {
          float v = acc[m][nn][r];
          sp += v * as[nn];
          dp += v * ad[nn];
          Cb[(size_t)row * NF + nn * 16 + lr] = f2bf(v);
        }
#pragma unroll
        for (int mk = 8; mk > 0; mk >>= 1) {
          sp += __shfl_xor(sp, mk);
          dp += __shfl_xor(dp, mk);
        }
        if (lr == 0) { sv[row] = sp; dv[row] = dp; }
      }
    }
  } else if (MODE == 1) {
    float bcol[8];
#pragma unroll
    for (int nn = 0; nn < 8; nn++) bcol[nn] = bias[nn * 16 + lr];
#pragma unroll
    for (int m = 0; m < 2; m++)
#pragma unroll
      for (int r = 0; r < 4; r++) {
        int row = row0 + m * 16 + lh * 4 + r;
        if (row < n) {
#pragma unroll
          for (int nn = 0; nn < 8; nn++)
            Cf[(size_t)row * NF + nn * 16 + lr] = acc[m][nn][r] + bcol[nn];
        }
      }
  } else {
    float bcol[8];
#pragma unroll
    for (int nn = 0; nn < 8; nn++) bcol[nn] = bias[nn * 16 + lr];
#pragma unroll
    for (int m = 0; m < 2; m++)
#pragma unroll
      for (int r = 0; r < 4; r++) {
        int row = row0 + m * 16 + lh * 4 + r;
#pragma unroll
        for (int nn = 0; nn < 8; nn++)
          Cb[(size_t)row * NF + nn * 16 + lr] = f2bf(acc[m][nn][r] + bcol[nn]);
      }
  }
}

// ---------------- fused softmax + gather + BN partial stats ----------------
// 256 thr = 4 waves; wave handles 4 nodes serially.
// 4 groups of 16 lanes; lane covers 8 cols (uint4 = 16B). 2 loads unrolled
// per iter -> 8 edges in flight per wave.
// All __shfl are UNCONDITIONAL (wave fully active); lanes l >= deg carry
// wj == 0, so out-of-range edge slots self-nullify (round-4 lesson).

__global__ __launch_bounds__(256) void k_attn_gather(
    const float* __restrict__ sv, const float* __restrict__ dv,
    const int* __restrict__ offs, const int* __restrict__ csr,
    const unsigned short* __restrict__ hbf, const float* __restrict__ bias,
    unsigned short* __restrict__ aggb, float* __restrict__ pstat, int n) {
  int w = threadIdx.x >> 6, l = threadIdx.x & 63;
  int ll = l & 15, g = l >> 4;
  int node0 = blockIdx.x * 16 + w * 4;
  float ps[8] = {0.f, 0.f, 0.f, 0.f, 0.f, 0.f, 0.f, 0.f};
  float qs[8] = {0.f, 0.f, 0.f, 0.f, 0.f, 0.f, 0.f, 0.f};
  float4 bv0 = *(const float4*)&bias[8 * ll];
  float4 bv1 = *(const float4*)&bias[8 * ll + 4];

  for (int ni = 0; ni < 4; ni++) {
    int node = node0 + ni;
    if (node >= n) break;
    int o0 = offs[node], o1 = offs[node + 1];
    int deg = o1 - o0;
    float di = dv[node];
    float a[8] = {0.f, 0.f, 0.f, 0.f, 0.f, 0.f, 0.f, 0.f};

    if (deg <= 64) {
      bool valid = l < deg;
      int srcj = valid ? csr[o0 + l] : 0;
      float ev = valid ? sv[srcj] + di : -1e30f;
      ev = ev >= 0.f ? ev : SLOPE * ev;
      float m = ev;
#pragma unroll
      for (int k2 = 32; k2 > 0; k2 >>= 1) m = fmaxf(m, __shfl_xor(m, k2));
      float pe = valid ? __expf(ev - m) : 0.f;
      float z = pe;
#pragma unroll
      for (int k2 = 32; k2 > 0; k2 >>= 1) z += __shfl_xor(z, k2);
      float wj = pe / z;  // == 0 for lanes l >= deg

      for (int t2 = 0; t2 < deg; t2 += 8) {
        int ta = t2 + g;        // <= 59, no wrap
        int tb = t2 + 4 + g;    // <= 63, no wrap
        int sA = __shfl(srcj, ta);       // unconditional: full wave active
        int sB = __shfl(srcj, tb);
        float wA = __shfl(wj, ta);       // wj==0 beyond deg -> auto-null
        float wB = __shfl(wj, tb);
        uint4 hA = *(const uint4*)(hbf + (size_t)sA * NF + 8 * ll);
        uint4 hB = *(const uint4*)(hbf + (size_t)sB * NF + 8 * ll);
        a[0] += wA * bflo(hA.x) + wB * bflo(hB.x);
        a[1] += wA * bfhi(hA.x) + wB * bfhi(hB.x);
        a[2] += wA * bflo(hA.y) + wB * bflo(hB.y);
        a[3] += wA * bfhi(hA.y) + wB * bfhi(hB.y);
        a[4] += wA * bflo(hA.z) + wB * bflo(hB.z);
        a[5] += wA * bfhi(hA.z) + wB * bfhi(hB.z);
        a[6] += wA * bflo(hA.w) + wB * bflo(hB.w);
        a[7] += wA * bfhi(hA.w) + wB * bfhi(hB.w);
      }
    } else {
      float m = -1e30f;
      for (int j = o0 + l; j < o1; j += 64) {
        float ev = sv[csr[j]] + di;
        ev = ev >= 0.f ? ev : SLOPE * ev;
        m = fmaxf(m, ev);
      }
#pragma unroll
      for (int k2 = 32; k2 > 0; k2 >>= 1) m = fmaxf(m, __shfl_xor(m, k2));
      float z = 0.f;
      for (int j = o0 + l; j < o1; j += 64) {
        float ev = sv[csr[j]] + di;
        ev = ev >= 0.f ? ev : SLOPE * ev;
        z += __expf(ev - m);
      }
#pragma unroll
      for (int k2 = 32; k2 > 0; k2 >>= 1) z += __shfl_xor(z, k2);
      float inv = 1.f / z;
      for (int t2 = 0; t2 < deg; t2 += 4) {
        int tt = t2 + g;
        if (tt < deg) {  // divergent, but contains no shfl -> safe
          int sI = csr[o0 + tt];
          float ev = sv[sI] + di;
          ev = ev >= 0.f ? ev : SLOPE * ev;
          float wI = __expf(ev - m) * inv;
          uint4 hv = *(const uint4*)(hbf + (size_t)sI * NF + 8 * ll);
          a[0] += wI * bflo(hv.x);
          a[1] += wI * bfhi(hv.x);
          a[2] += wI * bflo(hv.y);
          a[3] += wI * bfhi(hv.y);
          a[4] += wI * bflo(hv.z);
          a[5] += wI * bfhi(hv.z);
          a[6] += wI * bflo(hv.w);
          a[7] += wI * bfhi(hv.w);
        }
      }
    }
#pragma unroll
    for (int j = 0; j < 8; j++) {
      a[j] += __shfl_xor(a[j], 16);
      a[j] += __shfl_xor(a[j], 32);
    }
    if (g == 0) {
      a[0] += bv0.x; a[1] += bv0.y; a[2] += bv0.z; a[3] += bv0.w;
      a[4] += bv1.x; a[5] += bv1.y; a[6] += bv1.z; a[7] += bv1.w;
      uint4 ov;
      ov.x = pack2(a[0], a[1]);
      ov.y = pack2(a[2], a[3]);
      ov.z = pack2(a[4], a[5]);
      ov.w = pack2(a[6], a[7]);
      *(uint4*)(aggb + (size_t)node * NF + 8 * ll) = ov;
#pragma unroll
      for (int j = 0; j < 8; j++) { ps[j] += a[j]; qs[j] += a[j] * a[j]; }
    }
  }

  __shared__ float red[4][16][17];
  if (g == 0) {
#pragma unroll
    for (int j = 0; j < 8; j++) {
      red[w][ll][j] = ps[j];
      red[w][ll][8 + j] = qs[j];
    }
  }
  __syncthreads();
  int t = threadIdx.x;
  int c = t & 127, kind = t >> 7;
  int li = c >> 3, sj = (c & 7) + 8 * kind;
  float v = red[0][li][sj] + red[1][li][sj] + red[2][li][sj] + red[3][li][sj];
  atomicAdd(&pstat[(blockIdx.x & 63) * 256 + t], v);
}

// ---------------- BN finalize ----------------

__global__ void k_bnfinal(float* __restrict__ pstat, const float* __restrict__ gamma,
                          const float* __restrict__ beta, float* __restrict__ scsh,
                          float ninv) {
  __shared__ float tot[256];
  int t = threadIdx.x;
  float v = 0.f;
  for (int s2 = 0; s2 < 64; s2++) {
    v += pstat[s2 * 256 + t];
    pstat[s2 * 256 + t] = 0.f;
  }
  tot[t] = v;
  __syncthreads();
  if (t < 128) {
    float mu = tot[t] * ninv;
    float var = tot[128 + t] * ninv - mu * mu;
    float sc = gamma[t] * rsqrtf(var + EPS);
    scsh[t] = sc;
    scsh[128 + t] = beta[t] - mu * sc;
  }
}

// ---------------- BN apply (+relu+residual), all bf16 ----------------

template <int RELU_RES>
__global__ __launch_bounds__(256) void k_bn_apply(
    const unsigned short* __restrict__ agg, const float* __restrict__ scsh,
    const unsigned short* __restrict__ res, unsigned short* __restrict__ out, int n) {
  int cq = threadIdx.x & 31;
  int c0 = cq * 4;
  float sc0 = scsh[c0], sc1 = scsh[c0 + 1], sc2 = scsh[c0 + 2], sc3 = scsh[c0 + 3];
  float sh0 = scsh[128 + c0], sh1 = scsh[128 + c0 + 1], sh2 = scsh[128 + c0 + 2],
        sh3 = scsh[128 + c0 + 3];
  for (int r = blockIdx.x * 8 + (threadIdx.x >> 5); r < n; r += gridDim.x * 8) {
    size_t i = (size_t)r * 32 + cq;
    ushort4 av = ((const ushort4*)agg)[i];
    float v0 = bf2f(av.x) * sc0 + sh0;
    float v1 = bf2f(av.y) * sc1 + sh1;
    float v2 = bf2f(av.z) * sc2 + sh2;
    float v3 = bf2f(av.w) * sc3 + sh3;
    if (RELU_RES) {
      ushort4 rv = ((const ushort4*)res)[i];
      v0 = fmaxf(v0, 0.f) + bf2f(rv.x);
      v1 = fmaxf(v1, 0.f) + bf2f(rv.y);
      v2 = fmaxf(v2, 0.f) + bf2f(rv.z);
      v3 = fmaxf(v3, 0.f) + bf2f(rv.w);
    }
    ((ushort4*)out)[i] = make_ushort4(f2bf(v0), f2bf(v1), f2bf(v2), f2bf(v3));
  }
}

// ---------------- launcher ----------------

extern "C" void kernel_launch(void* const* d_in, const int* in_sizes, int n_in,
                              void* d_out, int out_size, void* d_ws, size_t ws_size,
                              hipStream_t stream) {
  (void)n_in; (void)out_size; (void)ws_size;
  const float* x     = (const float*)d_in[0];
  const int*   ei    = (const int*)d_in[1];
  const float* W0    = (const float*)d_in[2];
  const float* asrc0 = (const float*)d_in[3];
  const float* adst0 = (const float*)d_in[4];
  const float* b0    = (const float*)d_in[5];
  const float* Wm    = (const float*)d_in[6];
  const float* asrcm = (const float*)d_in[7];
  const float* adstm = (const float*)d_in[8];
  const float* bm    = (const float*)d_in[9];
  const float* W5    = (const float*)d_in[10];
  const float* asrc5 = (const float*)d_in[11];
  const float* adst5 = (const float*)d_in[12];
  const float* b5    = (const float*)d_in[13];
  const float* gammas= (const float*)d_in[14];
  const float* betas = (const float*)d_in[15];
  const float* Wr    = (const float*)d_in[16];
  const float* br    = (const float*)d_in[17];
  const float* Wo    = (const float*)d_in[18];
  const float* bo    = (const float*)d_in[19];

  const int n = in_sizes[0] / NF;
  const int np = (n + 127) & ~127;
  const int e = in_sizes[1] / 2;
  const int tot = e + n;
  const int* srcp = ei;
  const int* dstp = ei + e;

  char* w = (char*)d_ws;
  auto carve = [&](size_t bytes) {
    char* p = w;
    w += (bytes + 255) & ~(size_t)255;
    return p;
  };
  unsigned short* h_bf    = (unsigned short*)carve((size_t)np * NF * 2);
  unsigned short* hlin_bf = (unsigned short*)carve((size_t)np * NF * 2);
  unsigned short* res_bf  = (unsigned short*)carve((size_t)np * NF * 2);
  unsigned short* agg_bf  = (unsigned short*)carve((size_t)n * NF * 2);
  unsigned short* Wt      = (unsigned short*)carve((size_t)8 * NF * NF * 2);
  float* sv      = (float*)carve((size_t)np * 4);
  float* dv      = (float*)carve((size_t)np * 4);
  int*   csr     = (int*)carve((size_t)tot * 4);
  int*   offsets = (int*)carve((size_t)(n + 1) * 4);
  int*   counts  = (int*)carve((size_t)n * 4);
  int*   pos     = (int*)carve((size_t)e * 4);
  int*   partials= (int*)carve(64 * 4);
  float* pstat   = (float*)carve(64 * 256 * 4);
  float* scsh    = (float*)carve(256 * 4);

  int nb = (n + 2047) / 2048;

  // one-time converts
  k_wt<<<(8 * NF * NF + 255) / 256, 256, 0, stream>>>(W0, Wm, W5, Wr, Wo, Wt);
  k_f32_to_bf16<<<(np * (NF / 4) + 255) / 256, 256, 0, stream>>>(x, h_bf, n, np);

  // CSR build
  k_init_counts<<<(n + 255) / 256, 256, 0, stream>>>(counts, n);
  k_count<<<(e + 255) / 256, 256, 0, stream>>>(dstp, counts, pos, e);
  k_scan_part<<<nb, 256, 0, stream>>>(counts, partials, n);
  k_scan_mid<<<1, 64, 0, stream>>>(partials, nb);
  k_scan_final<<<nb, 256, 0, stream>>>(counts, partials, offsets, n);
  k_selfloop<<<(n + 255) / 256, 256, 0, stream>>>(offsets, csr, n, tot);
  k_fill<<<(e + 255) / 256, 256, 0, stream>>>(srcp, dstp, offsets, pos, csr, e);

  hipMemsetAsync(pstat, 0, 64 * 256 * 4, stream);

  int gemm_grid = np / 128;

  // residual = bf16(x @ Wr + br)
  k_gemm_mfma<2><<<gemm_grid, 256, 0, stream>>>(h_bf, Wt + 6 * NF * NF, nullptr, nullptr,
                                                br, res_bf, nullptr, nullptr, nullptr, n);

  for (int L = 0; L < 6; L++) {
    const float *als, *ald, *bl;
    if (L == 0)      { als = asrc0; ald = adst0; bl = b0; }
    else if (L <= 4) { als = asrcm + (L - 1) * NF; ald = adstm + (L - 1) * NF; bl = bm + (L - 1) * NF; }
    else             { als = asrc5; ald = adst5; bl = b5; }

    k_gemm_mfma<0><<<gemm_grid, 256, 0, stream>>>(h_bf, Wt + (size_t)L * NF * NF,
                                                  als, ald, nullptr, hlin_bf, nullptr, sv, dv, n);
    k_attn_gather<<<(n + 15) / 16, 256, 0, stream>>>(sv, dv, offsets, csr, hlin_bf, bl,
                                                     agg_bf, pstat, n);
    k_bnfinal<<<1, 256, 0, stream>>>(pstat, gammas + L * NF, betas + L * NF, scsh, 1.0f / n);

    if (L < 5) {
      k_bn_apply<1><<<1024, 256, 0, stream>>>(agg_bf, scsh, (L == 0) ? res_bf : h_bf, h_bf, n);
    } else {
      k_bn_apply<0><<<1024, 256, 0, stream>>>(agg_bf, scsh, nullptr, hlin_bf, n);
      k_gemm_mfma<1><<<gemm_grid, 256, 0, stream>>>(hlin_bf, Wt + 7 * NF * NF, nullptr, nullptr,
                                                    bo, nullptr, (float*)d_out, nullptr, nullptr, n);
    }
  }
}